// Round 1
// baseline (268.532 us; speedup 1.0000x reference)
//
#include <hip/hip_runtime.h>
#include <hip/hip_bf16.h>
#include <math.h>

// Problem constants
#define B_   128
#define C_   256
#define K_   64     // HZ*WZ (corr rows)
#define N_   1024   // HX*WX (corr cols)
#define H_   32
#define W_   32
#define TC_  8
#define L_   64     // 2*H
#define EPS_ 1e-5f

// ---------------------------------------------------------------------------
// Kernel A: per-batch corr = z^T x  (64 x 1024, K=256), fused pooling.
// grid (16 n-tiles, 128 batches), block 256.
// Each block: 64k x 64n tile. Thread (tk,tn) in 16x16 layout owns 4x4 outputs.
// n-tile of 64 contiguous n == 2 full h-rows -> x_h complete in-block.
// x_w partial (2 of 32 h) -> LDS reduce then global atomicAdd into xcat.
// corr written straight into d_out.
// ---------------------------------------------------------------------------
__global__ __launch_bounds__(256) void kA_corr(const float* __restrict__ z,
                                               const float* __restrict__ x,
                                               float* __restrict__ corr,
                                               float* __restrict__ xcat)
{
    __shared__ float zs[64 * 64];  // [c][k] 16KB
    __shared__ float xs[64 * 64];  // [c][n] 16KB

    const int t   = blockIdx.x;          // n-tile index 0..15
    const int b   = blockIdx.y;
    const int tid = threadIdx.x;
    const int tk  = tid & 15;
    const int tn  = tid >> 4;
    const int k0  = tk * 4;
    const int n0  = tn * 4;

    const float* zb = z + (size_t)b * C_ * K_;
    const float* xb = x + (size_t)b * C_ * N_ + t * 64;

    float acc[4][4] = {};

    for (int cc = 0; cc < C_; cc += 64) {
        // cooperative load: 1024 float4 per tile, 4 per thread, coalesced
        #pragma unroll
        for (int i = 0; i < 4; ++i) {
            int f4  = tid + i * 256;
            int row = f4 >> 4;
            int col = (f4 & 15) << 2;
            *(float4*)&zs[row * 64 + col] =
                *(const float4*)&zb[(size_t)(cc + row) * K_ + col];
            *(float4*)&xs[row * 64 + col] =
                *(const float4*)&xb[(size_t)(cc + row) * N_ + col];
        }
        __syncthreads();

        #pragma unroll 8
        for (int c = 0; c < 64; ++c) {
            float4 zv = *(float4*)&zs[c * 64 + k0];
            float4 xv = *(float4*)&xs[c * 64 + n0];
            float za[4] = {zv.x, zv.y, zv.z, zv.w};
            float xa[4] = {xv.x, xv.y, xv.z, xv.w};
            #pragma unroll
            for (int i = 0; i < 4; ++i)
                #pragma unroll
                for (int j = 0; j < 4; ++j)
                    acc[i][j] = fmaf(za[i], xa[j], acc[i][j]);
        }
        __syncthreads();
    }

    // write corr tile (into d_out)
    float* cb = corr + (size_t)b * K_ * N_ + t * 64;
    #pragma unroll
    for (int i = 0; i < 4; ++i) {
        float4 v = make_float4(acc[i][0], acc[i][1], acc[i][2], acc[i][3]);
        *(float4*)&cb[(size_t)(k0 + i) * N_ + n0] = v;
    }

    // ---- pooling epilogue (reuse zs as scratch; main loop is done) ----
    float* pw = zs;          // [64][32]  w-partials
    float* ph = zs + 2048;   // [64][16]  per-(k, tn) row sums

    float rs[4];
    #pragma unroll
    for (int i = 0; i < 4; ++i)
        rs[i] = acc[i][0] + acc[i][1] + acc[i][2] + acc[i][3];
    #pragma unroll
    for (int i = 0; i < 4; ++i)
        ph[(k0 + i) * 16 + tn] = rs[i];

    if (tn < 8) {  // n0..n0+3 in [0,32): h_local = 0 part, plain store
        #pragma unroll
        for (int i = 0; i < 4; ++i)
            #pragma unroll
            for (int j = 0; j < 4; ++j)
                pw[(k0 + i) * 32 + n0 + j] = acc[i][j];
    }
    __syncthreads();
    if (tn >= 8) {  // h_local = 1 part: exactly one thread per (k,w)
        #pragma unroll
        for (int i = 0; i < 4; ++i)
            #pragma unroll
            for (int j = 0; j < 4; ++j)
                pw[(k0 + i) * 32 + (n0 - 32) + j] += acc[i][j];
    }
    __syncthreads();

    float* xcb = xcat + (size_t)b * K_ * L_;
    // x_h: complete for h = 2t, 2t+1 -> direct store
    if (tid < 128) {
        int k = tid >> 1, hl = tid & 1;
        float s = 0.f;
        #pragma unroll
        for (int q = 0; q < 8; ++q) s += ph[k * 16 + hl * 8 + q];
        xcb[k * L_ + 2 * t + hl] = s * (1.f / 32.f);
    }
    // x_w: partial over 2 h-rows -> atomic accumulate (16 blocks/batch)
    #pragma unroll
    for (int r = 0; r < 8; ++r) {
        int idx = tid + r * 256;
        int k = idx >> 5, w = idx & 31;
        atomicAdd(&xcb[k * L_ + 32 + w], pw[k * 32 + w] * (1.f / 32.f));
    }
}

// ---------------------------------------------------------------------------
// Kernel B: y_pre = conv1_w @ xcat + b1 ; accumulate BN stats (sum, sumsq)
// grid 128 (one block per batch), block 256. 2 outputs per thread.
// ---------------------------------------------------------------------------
__global__ __launch_bounds__(256) void kB_conv1(const float* __restrict__ xcat,
                                                const float* __restrict__ w1,
                                                const float* __restrict__ b1,
                                                float* __restrict__ ypre,
                                                float* __restrict__ stats)
{
    __shared__ float xc[64 * 64];   // 16KB
    __shared__ float w1s[TC_ * 64];
    __shared__ float ys[TC_ * 64];

    const int b   = blockIdx.x;
    const int tid = threadIdx.x;
    const float* xcb = xcat + (size_t)b * K_ * L_;

    #pragma unroll
    for (int i = 0; i < 4; ++i) {
        int f4 = tid + i * 256;
        *(float4*)&xc[f4 * 4] = *(const float4*)&xcb[f4 * 4];
    }
    if (tid < 128) *(float4*)&w1s[tid * 4] = *(const float4*)&w1[tid * 4];
    __syncthreads();

    const int o0 = tid >> 6;     // wave-uniform
    const int l  = tid & 63;
    float y0 = 0.f, y1 = 0.f;
    #pragma unroll 8
    for (int k = 0; k < 64; ++k) {
        float xv = xc[k * 64 + l];
        y0 = fmaf(w1s[o0 * 64 + k],        xv, y0);
        y1 = fmaf(w1s[(o0 + 4) * 64 + k],  xv, y1);
    }
    y0 += b1[o0];
    y1 += b1[o0 + 4];
    ypre[((size_t)b * TC_ + o0)     * L_ + l] = y0;
    ypre[((size_t)b * TC_ + o0 + 4) * L_ + l] = y1;
    ys[o0 * L_ + l]       = y0;
    ys[(o0 + 4) * L_ + l] = y1;
    __syncthreads();

    if (tid < TC_) {
        float s = 0.f, sq = 0.f;
        for (int q = 0; q < L_; ++q) {
            float v = ys[tid * L_ + q];
            s += v;
            sq = fmaf(v, v, sq);
        }
        atomicAdd(&stats[tid],       s);
        atomicAdd(&stats[TC_ + tid], sq);
    }
}

// ---------------------------------------------------------------------------
// Kernel D: BN apply + h-swish, then out_h = sigmoid(conv2 @ yh + b2),
//           out_w = sigmoid(conv3 @ yw + b3). grid 128, block 256.
// ---------------------------------------------------------------------------
__global__ __launch_bounds__(256) void kD_gate(const float* __restrict__ ypre,
                                               const float* __restrict__ stats,
                                               const float* __restrict__ gamma,
                                               const float* __restrict__ beta,
                                               const float* __restrict__ w2,
                                               const float* __restrict__ b2,
                                               const float* __restrict__ w3,
                                               const float* __restrict__ b3,
                                               float* __restrict__ outh,
                                               float* __restrict__ outw)
{
    __shared__ float yn[TC_ * L_];          // 512
    __shared__ float w2s[K_ * TC_];         // 512
    __shared__ float w3s[K_ * TC_];         // 512
    __shared__ float b2s[K_], b3s[K_];

    const int b   = blockIdx.x;
    const int tid = threadIdx.x;
    const float inv_n = 1.f / (float)(B_ * L_);

    #pragma unroll
    for (int r = 0; r < 2; ++r) {
        int idx = tid + r * 256;            // 0..511
        int o   = idx >> 6;
        float mu  = stats[o] * inv_n;
        float var = stats[TC_ + o] * inv_n - mu * mu;
        float v = ypre[(size_t)b * TC_ * L_ + idx];
        v = (v - mu) * (1.f / sqrtf(var + EPS_)) * gamma[o] + beta[o];
        v = v * fminf(fmaxf(v + 3.f, 0.f), 6.f) * (1.f / 6.f);   // h_swish
        yn[idx] = v;
    }
    if (tid < 128)      *(float4*)&w2s[tid * 4]         = *(const float4*)&w2[tid * 4];
    else                *(float4*)&w3s[(tid - 128) * 4] = *(const float4*)&w3[(tid - 128) * 4];
    if (tid < 64)       b2s[tid]       = b2[tid];
    else if (tid < 128) b3s[tid - 64]  = b3[tid - 64];
    __syncthreads();

    #pragma unroll
    for (int r = 0; r < 16; ++r) {
        int idx   = tid + r * 256;          // 0..4095
        int which = idx >> 11;              // 0: out_h, 1: out_w
        int o     = (idx >> 5) & 63;
        int p     = idx & 31;
        const float* wsm = which ? w3s : w2s;
        const float* bsm = which ? b3s : b2s;
        float s = bsm[o];
        #pragma unroll
        for (int tt = 0; tt < TC_; ++tt)
            s = fmaf(wsm[o * TC_ + tt], yn[tt * L_ + which * H_ + p], s);
        s = 1.f / (1.f + __expf(-s));
        float* dst = which ? outw : outh;
        dst[((size_t)b * K_ + o) * H_ + p] = s;
    }
}

// ---------------------------------------------------------------------------
// Kernel E: out = corr * out_w[w] * out_h[h], in place on d_out. float4.
// ---------------------------------------------------------------------------
__global__ __launch_bounds__(256) void kE_final(float* __restrict__ out,
                                                const float* __restrict__ outh,
                                                const float* __restrict__ outw)
{
    int idx = blockIdx.x * 256 + threadIdx.x;   // float4 index, 2,097,152 total
    int w4 = idx & 7;
    int h  = (idx >> 3) & 31;
    int bk = idx >> 8;                          // b*64 + k
    float4 c4 = ((const float4*)out)[idx];
    float  oh = outh[bk * H_ + h];
    float4 ow = *(const float4*)&outw[bk * H_ + w4 * 4];
    c4.x *= ow.x * oh;
    c4.y *= ow.y * oh;
    c4.z *= ow.z * oh;
    c4.w *= ow.w * oh;
    ((float4*)out)[idx] = c4;
}

// ---------------------------------------------------------------------------
extern "C" void kernel_launch(void* const* d_in, const int* in_sizes, int n_in,
                              void* d_out, int out_size, void* d_ws, size_t ws_size,
                              hipStream_t stream)
{
    const float* z     = (const float*)d_in[0];
    const float* x     = (const float*)d_in[1];
    const float* w1    = (const float*)d_in[2];
    const float* b1    = (const float*)d_in[3];
    const float* gamma = (const float*)d_in[4];
    const float* beta  = (const float*)d_in[5];
    const float* w2    = (const float*)d_in[6];
    const float* b2    = (const float*)d_in[7];
    const float* w3    = (const float*)d_in[8];
    const float* b3    = (const float*)d_in[9];
    float* out = (float*)d_out;
    float* ws  = (float*)d_ws;

    // workspace layout (floats)
    float* xcat  = ws;                       // B*64*64      = 524288
    float* stats = ws + 524288;              // 16
    float* ypre  = ws + 524304;              // B*8*64       = 65536
    float* outh  = ws + 589840;              // B*64*32      = 262144
    float* outw  = ws + 852  - 0 + 851984 - 852; // (computed below)
    outw = ws + 851984;                      // B*64*32      = 262144

    // zero xcat + stats (ws is poisoned 0xAA before every launch)
    hipMemsetAsync(ws, 0, (size_t)(524288 + 16) * sizeof(float), stream);

    kA_corr <<<dim3(16, B_), 256, 0, stream>>>(z, x, out, xcat);
    kB_conv1<<<B_,          256, 0, stream>>>(xcat, w1, b1, ypre, stats);
    kD_gate <<<B_,          256, 0, stream>>>(ypre, stats, gamma, beta,
                                              w2, b2, w3, b3, outh, outw);
    kE_final<<<(B_ * K_ * N_) / (256 * 4), 256, 0, stream>>>(out, outh, outw);
}